// Round 3
// baseline (490.672 us; speedup 1.0000x reference)
//
#include <hip/hip_runtime.h>
#include <stdint.h>

#define HH 8
#define NN 256
#define DD 16
#define NWIN 64
#define LOG2E 1.44269504088896340736f

typedef __attribute__((ext_vector_type(8))) short short8;
typedef __attribute__((ext_vector_type(4))) float f32x4;

static __device__ __forceinline__ unsigned short f2bf(float f) {
    uint32_t u = __builtin_bit_cast(uint32_t, f);
    return (unsigned short)((u + 0x7fffu + ((u >> 16) & 1u)) >> 16);   // RTNE
}
static __device__ __forceinline__ uint32_t rne(uint32_t u) {
    return u + 0x7fffu + ((u >> 16) & 1u);
}
static __device__ __forceinline__ uint32_t pk2bf(float a, float b) {   // [b:a] packed bf16
    uint32_t ua = __builtin_bit_cast(uint32_t, a);
    uint32_t ub = __builtin_bit_cast(uint32_t, b);
    return (rne(ua) >> 16) | (rne(ub) & 0xffff0000u);
}
static __device__ __forceinline__ float blo(uint32_t u) {
    return __builtin_bit_cast(float, u << 16);
}
static __device__ __forceinline__ float bhi(uint32_t u) {
    return __builtin_bit_cast(float, u & 0xffff0000u);
}

// layout offset: o = h*65536 + it*4096 + jth*512 + q*128 + c*8 + jtl*4 + r
// ---------- biasD[h][it][jth][q][c][jtl][r] (bf16, pre-scaled by log2e) ----------
__global__ void bias_perm_kernel(const float* __restrict__ table,
                                 const int* __restrict__ index,
                                 unsigned short* __restrict__ biasD) {
    int o = blockIdx.x * 256 + threadIdx.x;   // 524288 total
    int r   = o & 3;
    int jtl = (o >> 2) & 1;
    int cc  = (o >> 3) & 15;
    int qq  = (o >> 7) & 3;
    int jth = (o >> 9) & 7;
    int it  = (o >> 12) & 15;
    int h   = o >> 16;
    int i = it * 16 + cc;
    int j = (jth * 2 + jtl) * 16 + qq * 4 + r;
    biasD[o] = f2bf(table[index[i * NN + j] * HH + h] * LOG2E);
}

// ---------- maskD[w][it][jth][q][c][jtl][r] (bf16, pre-scaled) ----------
__global__ void mask_perm_kernel(const float* __restrict__ mask,
                                 unsigned short* __restrict__ maskD) {
    int o = blockIdx.x * 256 + threadIdx.x;   // 4194304 total
    int r   = o & 3;
    int jtl = (o >> 2) & 1;
    int cc  = (o >> 3) & 15;
    int qq  = (o >> 7) & 3;
    int jth = (o >> 9) & 7;
    int it  = (o >> 12) & 15;
    int w   = o >> 16;
    int i = it * 16 + cc;
    int j = (jth * 2 + jtl) * 16 + qq * 4 + r;
    maskD[o] = f2bf(mask[((size_t)w * NN + i) * NN + j] * LOG2E);
}

// ---------- main fused attention: one block per (b,h) ----------
__global__ __launch_bounds__(256, 4) void attn_kernel(
    const float* __restrict__ q, const float* __restrict__ k, const float* __restrict__ v,
    const unsigned short* __restrict__ biasD, const unsigned short* __restrict__ maskD,
    float* __restrict__ out)
{
    int bh = blockIdx.x;
    int b  = bh >> 3;
    int h  = bh & 7;
    int w  = b & (NWIN - 1);
    int tid  = threadIdx.x;
    int lane = tid & 63;
    int wave = tid >> 6;
    int c    = lane & 15;
    int quad = lane >> 4;

    // Kf[(jt*2 + khalf)*16 + c][8 shorts]: K fragment rows, b128-loadable
    __shared__ __align__(16) unsigned short Kf[256 * 16];   // 8192 B
    __shared__ __align__(16) unsigned short Vl[4096];       // 8192 B
    // total LDS = 16 KB

    const size_t base = (size_t)bh * (NN * DD);

    // ---- stage Kf: thread t normalizes K row t, writes 2 fragment chunks ----
    {
        int jt = tid >> 4, cc = tid & 15;
        const float4* kr = (const float4*)(k + base + (size_t)tid * DD);
        float4 a0 = kr[0], a1 = kr[1], a2 = kr[2], a3 = kr[3];
        float x[16] = {a0.x,a0.y,a0.z,a0.w, a1.x,a1.y,a1.z,a1.w,
                       a2.x,a2.y,a2.z,a2.w, a3.x,a3.y,a3.z,a3.w};
        float ss = 0.f;
#pragma unroll
        for (int e = 0; e < 16; e++) ss += x[e] * x[e];
        float sc = 1.0f / fmaxf(sqrtf(ss), 1e-12f);
        uint32_t p[8];
#pragma unroll
        for (int e = 0; e < 8; e++) p[e] = pk2bf(x[2*e] * sc, x[2*e+1] * sc);
        uint4 w0 = {p[0], p[1], p[2], p[3]};
        uint4 w1 = {p[4], p[5], p[6], p[7]};
        *(uint4*)&Kf[((jt * 2 + 0) * 16 + cc) * 8] = w0;
        *(uint4*)&Kf[((jt * 2 + 1) * 16 + cc) * 8] = w1;
    }
    // ---- stage Vl (slot-permuted V^T fragments, bf16) ----
    {
        const float4* vr = (const float4*)(v + base + (size_t)tid * DD);
        float4 a0 = vr[0], a1 = vr[1], a2 = vr[2], a3 = vr[3];
        float x[16] = {a0.x,a0.y,a0.z,a0.w, a1.x,a1.y,a1.z,a1.w,
                       a2.x,a2.y,a2.z,a2.w, a3.x,a3.y,a3.z,a3.w};
        int j  = tid;
        int kc = j >> 5, hi = (j >> 4) & 1, qv = (j >> 2) & 3, r = j & 3;
        int jj = hi * 4 + r;
#pragma unroll
        for (int d = 0; d < 16; d++)
            Vl[((kc * 4 + qv) * 16 + d) * 8 + jj] = f2bf(x[d]);
    }
    __syncthreads();

    const unsigned short* Kbase = &Kf[((quad & 1) * 16 + c) * 8];
    f32x4 zero = {0.f, 0.f, 0.f, 0.f};

#pragma unroll 1
    for (int t = 0; t < 4; t++) {
        int it = wave * 4 + t;
        int i0 = it * 16;

        // ---- Q fragment (B-operand): Qn[i0+c][d=quad*8+jj], quads>=2 zero ----
        short8 qf = {0,0,0,0,0,0,0,0};
        if (quad < 2) {
            const float4* qr = (const float4*)(q + base + (size_t)(i0 + c) * DD + quad * 8);
            float4 a0 = qr[0], a1 = qr[1];
            float x[8] = {a0.x,a0.y,a0.z,a0.w, a1.x,a1.y,a1.z,a1.w};
            float ss = 0.f;
#pragma unroll
            for (int e = 0; e < 8; e++) ss += x[e] * x[e];
            ss += __shfl_xor(ss, 16);
            float sc = LOG2E / fmaxf(sqrtf(ss), 1e-12f);   // fold log2e into Q
            union { short8 s; uint32_t u[4]; } pq;
#pragma unroll
            for (int e = 0; e < 4; e++) pq.u[e] = pk2bf(x[2*e] * sc, x[2*e+1] * sc);
            qf = pq.s;
        }

        // ---- S^T = Kn*Qn^T with bias+mask as MFMA C-operand ----
        const unsigned short* bB = biasD + ((h * 16 + it) * 4096 + quad * 128 + c * 8);
        const unsigned short* mB = maskD + ((w * 16 + it) * 4096 + quad * 128 + c * 8);
        f32x4 acc[16];
#pragma unroll
        for (int jth = 0; jth < 8; jth++) {
            uint4 bu = *(const uint4*)(bB + jth * 512);
            uint4 mu = *(const uint4*)(mB + jth * 512);
            f32x4 c0, c1;
            c0[0] = blo(bu.x) + blo(mu.x); c0[1] = bhi(bu.x) + bhi(mu.x);
            c0[2] = blo(bu.y) + blo(mu.y); c0[3] = bhi(bu.y) + bhi(mu.y);
            c1[0] = blo(bu.z) + blo(mu.z); c1[1] = bhi(bu.z) + bhi(mu.z);
            c1[2] = blo(bu.w) + blo(mu.w); c1[3] = bhi(bu.w) + bhi(mu.w);
            short8 kf0 = *(const short8*)(Kbase + (jth * 2 + 0) * 256);
            short8 kf1 = *(const short8*)(Kbase + (jth * 2 + 1) * 256);
            acc[jth * 2 + 0] = __builtin_amdgcn_mfma_f32_16x16x32_bf16(kf0, qf, c0, 0, 0, 0);
            acc[jth * 2 + 1] = __builtin_amdgcn_mfma_f32_16x16x32_bf16(kf1, qf, c1, 0, 0, 0);
        }

        // ---- softmax over j (full row in registers across quads) ----
        float mx = -1e30f;
#pragma unroll
        for (int jt = 0; jt < 16; jt++) {
            mx = fmaxf(mx, fmaxf(fmaxf(acc[jt][0], acc[jt][1]),
                                 fmaxf(acc[jt][2], acc[jt][3])));
        }
        mx = fmaxf(mx, __shfl_xor(mx, 16));
        mx = fmaxf(mx, __shfl_xor(mx, 32));
        float sum = 0.f;
#pragma unroll
        for (int jt = 0; jt < 16; jt++) {
#pragma unroll
            for (int r = 0; r < 4; r++) {
                float e = __builtin_amdgcn_exp2f(acc[jt][r] - mx);
                acc[jt][r] = e;
                sum += e;
            }
        }
        sum += __shfl_xor(sum, 16);
        sum += __shfl_xor(sum, 32);
        float rs = __builtin_amdgcn_rcpf(sum);

        // ---- PV on unnormalized exp; dual accumulators; scale by rs at end ----
        f32x4 xa = zero, xb = zero;
#pragma unroll
        for (int kc = 0; kc < 8; kc += 2) {
            short8 vfa = *(const short8*)&Vl[((kc * 4 + quad) * 16 + c) * 8];
            short8 vfb = *(const short8*)&Vl[(((kc + 1) * 4 + quad) * 16 + c) * 8];
            union { short8 s; uint32_t u[4]; } pa, pb;
#pragma unroll
            for (int hi = 0; hi < 2; hi++) {
                int jt = kc * 2 + hi;
                pa.u[hi * 2 + 0] = pk2bf(acc[jt][0], acc[jt][1]);
                pa.u[hi * 2 + 1] = pk2bf(acc[jt][2], acc[jt][3]);
                int ju = (kc + 1) * 2 + hi;
                pb.u[hi * 2 + 0] = pk2bf(acc[ju][0], acc[ju][1]);
                pb.u[hi * 2 + 1] = pk2bf(acc[ju][2], acc[ju][3]);
            }
            xa = __builtin_amdgcn_mfma_f32_16x16x32_bf16(vfa, pa.s, xa, 0, 0, 0);
            xb = __builtin_amdgcn_mfma_f32_16x16x32_bf16(vfb, pb.s, xb, 0, 0, 0);
        }

        // ---- direct store: lane holds X[i0+c][quad*4 .. +3] ----
        float4 val;
        val.x = (xa[0] + xb[0]) * rs;
        val.y = (xa[1] + xb[1]) * rs;
        val.z = (xa[2] + xb[2]) * rs;
        val.w = (xa[3] + xb[3]) * rs;
        float4* dst = (float4*)(out + ((size_t)(b * NN + i0 + c)) * (HH * DD)
                                + h * DD + quad * 4);
        *dst = val;
    }
}

extern "C" void kernel_launch(void* const* d_in, const int* in_sizes, int n_in,
                              void* d_out, int out_size, void* d_ws, size_t ws_size,
                              hipStream_t stream) {
    const float* q     = (const float*)d_in[0];
    const float* k     = (const float*)d_in[1];
    const float* v     = (const float*)d_in[2];
    const float* table = (const float*)d_in[3];
    const int*   index = (const int*)d_in[4];
    const float* mask  = (const float*)d_in[5];
    float* out = (float*)d_out;

    unsigned short* biasD = (unsigned short*)d_ws;                 // 1 MB
    unsigned short* maskD = biasD + (size_t)HH * NN * NN;          // 8 MB

    bias_perm_kernel<<<2048, 256, 0, stream>>>(table, index, biasD);
    mask_perm_kernel<<<16384, 256, 0, stream>>>(mask, maskD);
    attn_kernel<<<4096, 256, 0, stream>>>(q, k, v, biasD, maskD, out);
}